// Round 18
// baseline (74.385 us; speedup 1.0000x reference)
//
#include <hip/hip_runtime.h>
#include <math.h>

#define IMG   512
#define NIMG  48
#define TB    64            // output tile rows
#define TC    32            // output tile cols
#define SR    74            // stat rows = TB + 10
#define PITCH 77            // odd pitch (R9-validated bijective-bank construction)
#define STS   (TC * PITCH)  // float2 elements per plane
#define NBLK  1024          // persistent: 4 blocks/CU x 256 CUs, ONE launch round
#define NTILE 6             // 6144 tiles / 1024 blocks
#define C1v   1.0e-4f
#define C2v   9.0e-4f

typedef __attribute__((ext_vector_type(2))) float f2;

struct Win { float w[11]; };

// R18: persistent-block test of the residency-churn hypothesis. R12-R17
// falsified VALU, LDS, HBM BW, load latency, and block granularity as the
// binding constraint; OccupancyPercent stuck at 57-68% despite 32 supplied
// waves points at inter-block launch/drain gaps (6 sequential rounds of
// 4 blocks/CU). Now: grid = exactly 1024 blocks = 4/CU, each looping 6 tiles
// (decode = shifts; tile body is R16's proven best verbatim). All waves stay
// resident the whole kernel. Occupancy is the verification bit.
template<bool GUARD>
__device__ __forceinline__ void phaseA_unit(
        float2* __restrict__ hs2,
        const float* __restrict__ P,
        const float* __restrict__ T,
        const Win& win, int bx, int y0, int x0, int u) {
    const int r  = u >> 3;
    const int cb = u & 7;
    const int gy = y0 - 5 + r;
    const float* __restrict__ Prow = P + (long)gy * IMG;
    const float* __restrict__ Trow = T + (long)gy * IMG;
    const bool yok = (!GUARD) || ((gy >= 0) & (gy < IMG));

    float s1[4], s2[4], q1[4], q2[4];
    #pragma unroll
    for (int i = 0; i < 4; ++i) { s1[i]=0.f; s2[i]=0.f; q1[i]=0.f; q2[i]=0.f; }

    // window words 0..19 in 5 aligned 16B chunks; words 3..16 used.
    #pragma unroll
    for (int k = 0; k < 5; ++k) {
        float4 p = make_float4(0.f, 0.f, 0.f, 0.f);
        float4 t = make_float4(0.f, 0.f, 0.f, 0.f);
        bool zero = false;
        if (GUARD)   // every 16B chunk fully in-image or fully padding (R8-proven)
            zero = (!yok) | ((bx == 0)  & (cb + k <= 1))
                          | ((bx == 15) & (cb + k >= 10));
        if (!zero) {
            const int gx = x0 + 4 * (cb + k - 2);
            p = *(const float4*)(Prow + gx);
            t = *(const float4*)(Trow + gx);
        }
        const float pv[4] = { p.x, p.y, p.z, p.w };
        const float tv[4] = { t.x, t.y, t.z, t.w };
        #pragma unroll
        for (int j4 = 0; j4 < 4; ++j4) {
            const int w = 4 * k + j4;
            if (w >= 3 && w <= 16) {
                const float sm = pv[j4] + tv[j4];
                const float dm = pv[j4] - tv[j4];
                const float sq = sm * sm;
                const float dq = dm * dm;
                #pragma unroll
                for (int i = 0; i < 4; ++i) {     // col i uses tap j = w-3-i
                    const int j = w - 3 - i;
                    if (j >= 0 && j < 11) {
                        const float wj = win.w[j];
                        s1[i] += wj * sm;
                        s2[i] += wj * dm;
                        q1[i] += wj * sq;
                        q2[i] += wj * dq;
                    }
                }
            }
        }
    }
    // paired b64 stores: elem = plane*STS + (4cb+i)*PITCH + r
    const int ebase = (4 * cb) * PITCH + r;
    #pragma unroll
    for (int i = 0; i < 4; ++i) {
        hs2[ebase + i * PITCH]       = make_float2(s1[i], s2[i]);
        hs2[STS + ebase + i * PITCH] = make_float2(q1[i], q2[i]);
    }
}

__device__ __forceinline__ float ssim_epilogue(float S1, float S2, float Q1, float Q2) {
    const float s1q = S1 * S1;
    const float s2q = S2 * S2;
    const float A_  = 0.5f * (s1q + s2q);     // mu1^2 + mu2^2
    const float B_  = 0.5f * (s1q - s2q);     // 2 mu1 mu2
    const float sps = 0.5f * (Q1 + Q2) - A_;  // sig1^2 + sig2^2
    const float sxx = 0.5f * (Q1 - Q2) - B_;  // 2 sig12
    const float num = (B_ + C1v) * (sxx + C2v);
    const float den = (A_ + C1v) * (sps + C2v);
    return num * __builtin_amdgcn_rcpf(den);
}

__global__ __launch_bounds__(512, 8) void ssim_kernel(
        const float* __restrict__ pred,
        const float* __restrict__ targ,
        float* __restrict__ partial, Win win) {
    __shared__ float2 hs2[2 * STS];
    __shared__ float wavesum[8];

    const int tid = threadIdx.x;
    const int p   = blockIdx.x;          // persistent block id, 0..1023

    float acc = 0.f;

    #pragma unroll 1
    for (int t = 0; t < NTILE; ++t) {
        const int tile = p + NBLK * t;   // 0..6143
        const int n  = tile >> 7;        // / 128  (16 bx * 8 by)
        const int rm = tile & 127;
        const int by = rm >> 4;          // 0..7
        const int bx = rm & 15;          // 0..15
        const int y0 = by * TB;
        const int x0 = bx * TC;

        const float* __restrict__ P = pred + (size_t)n * IMG * IMG;
        const float* __restrict__ T = targ + (size_t)n * IMG * IMG;

        // ---- phase A: H-pass from global; unit = (stat row r, col-quad cb) ----
        const bool guard = (bx == 0) | (bx == 15) | (by == 0) | (by == 7);
        if (guard) {
            #pragma unroll 1
            for (int u = tid; u < SR * 8; u += 512)
                phaseA_unit<true >(hs2, P, T, win, bx, y0, x0, u);
        } else {
            #pragma unroll 1
            for (int u = tid; u < SR * 8; u += 512)
                phaseA_unit<false>(hs2, P, T, win, bx, y0, x0, u);
        }
        __syncthreads();

        // ---- phase B: 256 threads; thread = (col x, row-octet ro), both planes ----
        if (tid < 256) {
            const int x  = tid & 31;
            const int ro = tid >> 5;      // 0..7
            const int r0 = ro * 8;
            const float2* __restrict__ csd = &hs2[x * PITCH + r0];         // (s1,s2)
            const float2* __restrict__ cqq = &hs2[STS + x * PITCH + r0];   // (q1,q2)

            f2 sumS[8], sumQ[8];
            #pragma unroll
            for (int k = 0; k < 8; ++k) { sumS[k] = (f2)0.f; sumQ[k] = (f2)0.f; }

            #pragma unroll
            for (int m = 0; m < 18; ++m) {    // ds_read2_b64-paired consecutive elems
                const float2 raw = csd[m];
                f2 v; v.x = raw.x; v.y = raw.y;
                #pragma unroll
                for (int k = 0; k < 8; ++k) { // output k uses tap j = m - k
                    const int j = m - k;
                    if (j >= 0 && j < 11)
                        sumS[k] += win.w[j] * v;   // v_pk_fma_f32
                }
            }
            #pragma unroll
            for (int m = 0; m < 18; ++m) {
                const float2 raw = cqq[m];
                f2 v; v.x = raw.x; v.y = raw.y;
                #pragma unroll
                for (int k = 0; k < 8; ++k) {
                    const int j = m - k;
                    if (j >= 0 && j < 11)
                        sumQ[k] += win.w[j] * v;
                }
            }

            #pragma unroll
            for (int k = 0; k < 8; ++k)
                acc += ssim_epilogue(sumS[k].x, sumS[k].y, sumQ[k].x, sumQ[k].y);
        }
        __syncthreads();                  // phase-B reads done before next tile's writes
    }

    // ---- block reduction (8 waves; waves 4-7 contribute 0) ----
    #pragma unroll
    for (int off = 32; off > 0; off >>= 1)
        acc += __shfl_down(acc, off, 64);
    const int wv = tid >> 6;
    if ((tid & 63) == 0) wavesum[wv] = acc;
    __syncthreads();
    if (tid == 0) {
        float s = 0.f;
        #pragma unroll
        for (int i = 0; i < 8; ++i) s += wavesum[i];
        partial[p] = s;
    }
}

__global__ __launch_bounds__(512) void ssim_reduce_kernel(
        const float* __restrict__ partial,
        float* __restrict__ out,
        int nchunk4, double inv_n) {
    __shared__ double wsum[8];
    const float4* __restrict__ p4 = (const float4*)partial;
    double s = 0.0;
    #pragma unroll 1
    for (int i = threadIdx.x; i < nchunk4; i += 512) {
        const float4 v = p4[i];
        s += (double)((v.x + v.y) + (v.z + v.w));
    }
    #pragma unroll
    for (int off = 32; off > 0; off >>= 1)
        s += __shfl_down(s, off, 64);
    const int wv = threadIdx.x >> 6;
    if ((threadIdx.x & 63) == 0) wsum[wv] = s;
    __syncthreads();
    if (threadIdx.x == 0) {
        double tot = 0.0;
        #pragma unroll
        for (int i = 0; i < 8; ++i) tot += wsum[i];
        out[0] = (float)(tot * inv_n);
    }
}

extern "C" void kernel_launch(void* const* d_in, const int* in_sizes, int n_in,
                              void* d_out, int out_size, void* d_ws, size_t ws_size,
                              hipStream_t stream) {
    const float* pred = (const float*)d_in[0];
    const float* targ = (const float*)d_in[1];
    float* out     = (float*)d_out;
    float* partial = (float*)d_ws;   // 1024 floats, all written

    Win win;
    {
        double v[11], s = 0.0;
        for (int i = 0; i < 11; ++i) {
            float d   = (float)i - 5.0f;
            float arg = -(d * d) / 4.5f;      // 2*sigma^2 = 4.5
            v[i] = exp((double)arg);
            s += v[i];
        }
        for (int i = 0; i < 11; ++i) win.w[i] = (float)(v[i] / s);
    }

    ssim_kernel<<<NBLK, 512, 0, stream>>>(pred, targ, partial, win);

    const double inv_n = 1.0 / ((double)NIMG * IMG * IMG);
    ssim_reduce_kernel<<<1, 512, 0, stream>>>(partial, out, NBLK / 4, inv_n);
}

// Round 19
// 53.442 us; speedup vs baseline: 1.3919x; 1.3919x over previous
//
#include <hip/hip_runtime.h>
#include <math.h>

#define IMG   512
#define NIMG  48
#define TB    64            // output tile rows
#define TC    32            // output tile cols
#define SR    74            // stat rows = TB + 10
#define PITCH 77            // odd pitch (R9-validated bijective-bank construction)
#define STS   (TC * PITCH)  // float2 elements per plane
#define C1v   1.0e-4f
#define C2v   9.0e-4f

typedef __attribute__((ext_vector_type(2))) float f2;

struct Win { float w[11]; };

// R19 = exact revert to R16 (best measured: 55.07us). R13-R18 post-mortems:
// every throughput lever (VALU diet, LDS -36%, HBM/L3 residency, load
// latency, finer blocks, persistent blocks) is either neutral or regresses
// via allocator spill. This structure's measured floor is ~55us with all
// true pipe utilizations <=45%; reproducing it is the final deliverable.
template<bool GUARD>
__device__ __forceinline__ void phaseA_unit(
        float2* __restrict__ hs2,
        const float* __restrict__ P,
        const float* __restrict__ T,
        const Win& win, int bx, int y0, int x0, int u) {
    const int r  = u >> 3;
    const int cb = u & 7;
    const int gy = y0 - 5 + r;
    const float* __restrict__ Prow = P + (long)gy * IMG;
    const float* __restrict__ Trow = T + (long)gy * IMG;
    const bool yok = (!GUARD) || ((gy >= 0) & (gy < IMG));

    float s1[4], s2[4], q1[4], q2[4];
    #pragma unroll
    for (int i = 0; i < 4; ++i) { s1[i]=0.f; s2[i]=0.f; q1[i]=0.f; q2[i]=0.f; }

    // window words 0..19 in 5 aligned 16B chunks; words 3..16 used.
    #pragma unroll
    for (int k = 0; k < 5; ++k) {
        float4 p = make_float4(0.f, 0.f, 0.f, 0.f);
        float4 t = make_float4(0.f, 0.f, 0.f, 0.f);
        bool zero = false;
        if (GUARD)   // every 16B chunk fully in-image or fully padding (R8-proven)
            zero = (!yok) | ((bx == 0)  & (cb + k <= 1))
                          | ((bx == 15) & (cb + k >= 10));
        if (!zero) {
            const int gx = x0 + 4 * (cb + k - 2);
            p = *(const float4*)(Prow + gx);
            t = *(const float4*)(Trow + gx);
        }
        const float pv[4] = { p.x, p.y, p.z, p.w };
        const float tv[4] = { t.x, t.y, t.z, t.w };
        #pragma unroll
        for (int j4 = 0; j4 < 4; ++j4) {
            const int w = 4 * k + j4;
            if (w >= 3 && w <= 16) {
                const float sm = pv[j4] + tv[j4];
                const float dm = pv[j4] - tv[j4];
                const float sq = sm * sm;
                const float dq = dm * dm;
                #pragma unroll
                for (int i = 0; i < 4; ++i) {     // col i uses tap j = w-3-i
                    const int j = w - 3 - i;
                    if (j >= 0 && j < 11) {
                        const float wj = win.w[j];
                        s1[i] += wj * sm;
                        s2[i] += wj * dm;
                        q1[i] += wj * sq;
                        q2[i] += wj * dq;
                    }
                }
            }
        }
    }
    // paired b64 stores: elem = plane*STS + (4cb+i)*PITCH + r
    const int ebase = (4 * cb) * PITCH + r;
    #pragma unroll
    for (int i = 0; i < 4; ++i) {
        hs2[ebase + i * PITCH]       = make_float2(s1[i], s2[i]);
        hs2[STS + ebase + i * PITCH] = make_float2(q1[i], q2[i]);
    }
}

__device__ __forceinline__ float ssim_epilogue(float S1, float S2, float Q1, float Q2) {
    const float s1q = S1 * S1;
    const float s2q = S2 * S2;
    const float A_  = 0.5f * (s1q + s2q);     // mu1^2 + mu2^2
    const float B_  = 0.5f * (s1q - s2q);     // 2 mu1 mu2
    const float sps = 0.5f * (Q1 + Q2) - A_;  // sig1^2 + sig2^2
    const float sxx = 0.5f * (Q1 - Q2) - B_;  // 2 sig12
    const float num = (B_ + C1v) * (sxx + C2v);
    const float den = (A_ + C1v) * (sps + C2v);
    return num * __builtin_amdgcn_rcpf(den);
}

__global__ __launch_bounds__(512, 8) void ssim_kernel(
        const float* __restrict__ pred,
        const float* __restrict__ targ,
        float* __restrict__ partial, Win win) {
    __shared__ float2 hs2[2 * STS];
    __shared__ float wavesum[8];

    const int tid = threadIdx.x;
    const int n   = blockIdx.z;
    const int by  = blockIdx.y;
    const int bx  = blockIdx.x;
    const int y0  = by * TB;
    const int x0  = bx * TC;

    const float* __restrict__ P = pred + (size_t)n * IMG * IMG;
    const float* __restrict__ T = targ + (size_t)n * IMG * IMG;

    // ---- phase A: H-pass from global; unit = (stat row r, col-quad cb) ----
    const bool guard = (bx == 0) | (bx == 15) | (by == 0) | (by == (IMG / TB - 1));
    if (guard) {
        #pragma unroll 1
        for (int u = tid; u < SR * 8; u += 512)
            phaseA_unit<true >(hs2, P, T, win, bx, y0, x0, u);
    } else {
        #pragma unroll 1
        for (int u = tid; u < SR * 8; u += 512)
            phaseA_unit<false>(hs2, P, T, win, bx, y0, x0, u);
    }
    __syncthreads();

    // ---- phase B: 256 threads; thread = (col x, row-octet ro), both planes ----
    float acc = 0.f;
    if (tid < 256) {
        const int x  = tid & 31;
        const int ro = tid >> 5;          // 0..7
        const int r0 = ro * 8;
        const float2* __restrict__ csd = &hs2[x * PITCH + r0];         // (s1,s2)
        const float2* __restrict__ cqq = &hs2[STS + x * PITCH + r0];   // (q1,q2)

        f2 sumS[8], sumQ[8];
        #pragma unroll
        for (int k = 0; k < 8; ++k) { sumS[k] = (f2)0.f; sumQ[k] = (f2)0.f; }

        #pragma unroll
        for (int m = 0; m < 18; ++m) {    // ds_read2_b64-paired consecutive elems
            const float2 raw = csd[m];
            f2 v; v.x = raw.x; v.y = raw.y;
            #pragma unroll
            for (int k = 0; k < 8; ++k) { // output k uses tap j = m - k
                const int j = m - k;
                if (j >= 0 && j < 11)
                    sumS[k] += win.w[j] * v;   // v_pk_fma_f32
            }
        }
        #pragma unroll
        for (int m = 0; m < 18; ++m) {
            const float2 raw = cqq[m];
            f2 v; v.x = raw.x; v.y = raw.y;
            #pragma unroll
            for (int k = 0; k < 8; ++k) {
                const int j = m - k;
                if (j >= 0 && j < 11)
                    sumQ[k] += win.w[j] * v;
            }
        }

        #pragma unroll
        for (int k = 0; k < 8; ++k)
            acc += ssim_epilogue(sumS[k].x, sumS[k].y, sumQ[k].x, sumQ[k].y);
    }

    // ---- block reduction (8 waves; waves 4-7 contribute 0) ----
    #pragma unroll
    for (int off = 32; off > 0; off >>= 1)
        acc += __shfl_down(acc, off, 64);
    const int wv = tid >> 6;
    if ((tid & 63) == 0) wavesum[wv] = acc;
    __syncthreads();
    if (tid == 0) {
        float s = 0.f;
        #pragma unroll
        for (int i = 0; i < 8; ++i) s += wavesum[i];
        const int bid = (blockIdx.z * gridDim.y + blockIdx.y) * gridDim.x + blockIdx.x;
        partial[bid] = s;
    }
}

__global__ __launch_bounds__(512) void ssim_reduce_kernel(
        const float* __restrict__ partial,
        float* __restrict__ out,
        int nchunk4, double inv_n) {
    __shared__ double wsum[8];
    const float4* __restrict__ p4 = (const float4*)partial;
    double s = 0.0;
    #pragma unroll 1
    for (int i = threadIdx.x; i < nchunk4; i += 512) {
        const float4 v = p4[i];
        s += (double)((v.x + v.y) + (v.z + v.w));
    }
    #pragma unroll
    for (int off = 32; off > 0; off >>= 1)
        s += __shfl_down(s, off, 64);
    const int wv = threadIdx.x >> 6;
    if ((threadIdx.x & 63) == 0) wsum[wv] = s;
    __syncthreads();
    if (threadIdx.x == 0) {
        double tot = 0.0;
        #pragma unroll
        for (int i = 0; i < 8; ++i) tot += wsum[i];
        out[0] = (float)(tot * inv_n);
    }
}

extern "C" void kernel_launch(void* const* d_in, const int* in_sizes, int n_in,
                              void* d_out, int out_size, void* d_ws, size_t ws_size,
                              hipStream_t stream) {
    const float* pred = (const float*)d_in[0];
    const float* targ = (const float*)d_in[1];
    float* out     = (float*)d_out;
    float* partial = (float*)d_ws;   // 16*8*48 = 6144 floats, all written

    Win win;
    {
        double v[11], s = 0.0;
        for (int i = 0; i < 11; ++i) {
            float d   = (float)i - 5.0f;
            float arg = -(d * d) / 4.5f;      // 2*sigma^2 = 4.5
            v[i] = exp((double)arg);
            s += v[i];
        }
        for (int i = 0; i < 11; ++i) win.w[i] = (float)(v[i] / s);
    }

    dim3 grid(IMG / TC, IMG / TB, NIMG);      // (16, 8, 48) = 6144 blocks
    ssim_kernel<<<grid, 512, 0, stream>>>(pred, targ, partial, win);

    const int nblk = (IMG / TC) * (IMG / TB) * NIMG;   // 6144 -> 1536 float4
    const double inv_n = 1.0 / ((double)NIMG * IMG * IMG);
    ssim_reduce_kernel<<<1, 512, 0, stream>>>(partial, out, nblk / 4, inv_n);
}